// Round 1
// baseline (119.305 us; speedup 1.0000x reference)
//
#include <hip/hip_runtime.h>

#define NB 16
#define SQL 2048
#define SKL 2048
#define DH 64

typedef __attribute__((ext_vector_type(8))) short bf16x8;
typedef __attribute__((ext_vector_type(4))) unsigned short u16x4;
typedef __attribute__((ext_vector_type(8))) unsigned short u16x8;
typedef __attribute__((ext_vector_type(4))) float f32x4;

#define LOG2E 1.4426950408889634f
#define K1 (0.125f * LOG2E)   // scale 1/sqrt(64) folded into exp2 argument

// fp32 -> bf16 round-to-nearest-even (normals; inputs are finite)
__device__ __forceinline__ unsigned short f2bf(float f) {
    unsigned int u = __builtin_bit_cast(unsigned int, f);
    u += 0x7fffu + ((u >> 16) & 1u);
    return (unsigned short)(u >> 16);
}

// ---------------------------------------------------------------------------
// Prep: Q,K fp32->bf16 (blocks 0..2047), V fp32 -> V^T bf16 (blocks 2048..2559)
// ---------------------------------------------------------------------------
__global__ __launch_bounds__(256) void prep_kernel(
    const float* __restrict__ Q, const float* __restrict__ K,
    const float* __restrict__ V,
    unsigned short* __restrict__ Qb, unsigned short* __restrict__ Kb,
    unsigned short* __restrict__ Vt) {
    const int blk = blockIdx.x;
    if (blk < 2048) {
        const float* src = (blk < 1024) ? Q : K;
        unsigned short* dst = (blk < 1024) ? Qb : Kb;
        const size_t base = ((size_t)(blk & 1023) * 256 + threadIdx.x) * 8;
        float4 a = *(const float4*)(src + base);
        float4 b = *(const float4*)(src + base + 4);
        u16x8 o;
        o[0] = f2bf(a.x); o[1] = f2bf(a.y); o[2] = f2bf(a.z); o[3] = f2bf(a.w);
        o[4] = f2bf(b.x); o[5] = f2bf(b.y); o[6] = f2bf(b.z); o[7] = f2bf(b.w);
        *(u16x8*)(dst + base) = o;
    } else {
        // V transpose: tile (64 keys x 64 d) -> Vt[b][d][k]
        const int t  = blk - 2048;          // 0..511
        const int b  = t >> 5;              // batch
        const int kb = (t & 31) << 6;       // key base
        __shared__ float tile[64][65];
        const int tid = threadIdx.x;
        {
            const int r  = tid >> 2;            // key row 0..63
            const int cg = (tid & 3) << 4;      // col group of 16
            const float* vsrc = V + ((size_t)b * SKL + (kb + r)) * DH;
            #pragma unroll
            for (int i = 0; i < 4; ++i) {
                float4 x = *(const float4*)(vsrc + cg + i * 4);
                tile[r][cg + i*4 + 0] = x.x;
                tile[r][cg + i*4 + 1] = x.y;
                tile[r][cg + i*4 + 2] = x.z;
                tile[r][cg + i*4 + 3] = x.w;
            }
        }
        __syncthreads();
        {
            const int d  = tid >> 2;            // d row 0..63
            const int kg = (tid & 3) << 4;      // 16 keys
            unsigned short* dst = Vt + ((size_t)b * DH + d) * SKL + kb + kg;
            u16x8 o0, o1;
            #pragma unroll
            for (int j = 0; j < 8; ++j) o0[j] = f2bf(tile[kg + j][d]);
            #pragma unroll
            for (int j = 0; j < 8; ++j) o1[j] = f2bf(tile[kg + 8 + j][d]);
            *(u16x8*)(dst)     = o0;
            *(u16x8*)(dst + 8) = o1;
        }
    }
}

// ---------------------------------------------------------------------------
// Flash attention, S^T/O^T formulation.
// Block = 256 thr (4 waves), Q-tile 64 rows (16/wave), K-tile 64 keys.
// Per lane: q-column = lane&15 -> m,l are scalars; per 16x16 S^T tile the lane
// holds 4 CONTIGUOUS keys (quad*4+reg) -> P spills to LDS as one b64 write.
// ---------------------------------------------------------------------------
__global__ __launch_bounds__(256, 2) void attn_kernel(
    const unsigned short* __restrict__ Qb,
    const unsigned short* __restrict__ Kb,
    const unsigned short* __restrict__ Vt,
    const int* __restrict__ valid_lens,
    float* __restrict__ out) {
    const int b    = blockIdx.y;
    const int qblk = blockIdx.x;
    const int tid  = threadIdx.x;
    const int wave = tid >> 6;
    const int lane = tid & 63;
    const int c16  = lane & 15;
    const int quad = lane >> 4;

    const int valid  = valid_lens[b];
    const int ntiles = (valid + 63) >> 6;

    __shared__ unsigned short Klds[64][72];          // [key][d]   pitch 72
    __shared__ unsigned short Vlds[64][72];          // [d][key]   pitch 72
    __shared__ unsigned short Plds[4][16][72];       // per-wave [q][key]

    // Q B-fragments (loop-invariant): B[k=d][n=q] -> lane n=c16, k=quad*8+j
    const int q0 = qblk * 64 + wave * 16;
    const unsigned short* qptr = Qb + ((size_t)b * SQL + q0 + c16) * DH;
    const bf16x8 qf0 = *(const bf16x8*)(qptr + quad * 8);
    const bf16x8 qf1 = *(const bf16x8*)(qptr + 32 + quad * 8);

    const unsigned short* kbase = Kb + (size_t)b * SKL * DH;
    const unsigned short* vbase = Vt + (size_t)b * DH * SKL;

    const f32x4 zero = {0.f, 0.f, 0.f, 0.f};
    f32x4 o[4];
    #pragma unroll
    for (int i = 0; i < 4; ++i) o[i] = zero;
    float mrow = -1e30f, lrow = 0.f;

    for (int kt = 0; kt < ntiles; ++kt) {
        const int kb = kt << 6;
        // ---- stage K-tile and V^T-tile (bf16, 16B chunks) ----
        #pragma unroll
        for (int i = 0; i < 2; ++i) {
            const int c   = i * 256 + tid;      // 0..511
            const int r   = c >> 3;
            const int col = (c & 7) << 3;
            *(u16x8*)&Klds[r][col] = *(const u16x8*)(kbase + (size_t)(kb + r) * DH + col);
            *(u16x8*)&Vlds[r][col] = *(const u16x8*)(vbase + (size_t)r * SKL + kb + col);
        }
        __syncthreads();

        // ---- S^T = K . Q^T : 4 key-tiles x (K=64 over 2 mfma) ----
        f32x4 s[4];
        #pragma unroll
        for (int t = 0; t < 4; ++t) {
            s[t] = zero;
            const bf16x8 kf0 = *(const bf16x8*)&Klds[t * 16 + c16][quad * 8];
            const bf16x8 kf1 = *(const bf16x8*)&Klds[t * 16 + c16][32 + quad * 8];
            s[t] = __builtin_amdgcn_mfma_f32_16x16x32_bf16(kf0, qf0, s[t], 0, 0, 0);
            s[t] = __builtin_amdgcn_mfma_f32_16x16x32_bf16(kf1, qf1, s[t], 0, 0, 0);
        }

        // ---- mask (only boundary tile takes this path; wave-uniform) ----
        if (kb + 64 > valid) {
            #pragma unroll
            for (int t = 0; t < 4; ++t)
                #pragma unroll
                for (int r = 0; r < 4; ++r)
                    if (kb + t * 16 + quad * 4 + r >= valid) s[t][r] = -1e30f;
        }

        // ---- online softmax; q-column is per-lane scalar state ----
        float tmax = -1e30f;
        #pragma unroll
        for (int t = 0; t < 4; ++t)
            #pragma unroll
            for (int r = 0; r < 4; ++r) tmax = fmaxf(tmax, s[t][r]);
        tmax = fmaxf(tmax, __shfl_xor(tmax, 16));
        tmax = fmaxf(tmax, __shfl_xor(tmax, 32));

        const float mnew  = fmaxf(mrow, 0.125f * tmax);
        const float alpha = exp2f((mrow - mnew) * LOG2E);
        const float mk    = mnew * LOG2E;
        float rs = 0.f;
        #pragma unroll
        for (int t = 0; t < 4; ++t)
            #pragma unroll
            for (int r = 0; r < 4; ++r) {
                const float p = exp2f(fmaf(s[t][r], K1, -mk));
                s[t][r] = p;
                rs += p;
            }
        rs += __shfl_xor(rs, 16);
        rs += __shfl_xor(rs, 32);
        lrow = lrow * alpha + rs;
        mrow = mnew;
        #pragma unroll
        for (int i = 0; i < 4; ++i) o[i] *= alpha;

        // ---- P -> LDS (bf16), 4 contiguous keys per write ----
        #pragma unroll
        for (int t = 0; t < 4; ++t) {
            u16x4 pw;
            pw[0] = f2bf(s[t][0]); pw[1] = f2bf(s[t][1]);
            pw[2] = f2bf(s[t][2]); pw[3] = f2bf(s[t][3]);
            *(u16x4*)&Plds[wave][c16][t * 16 + quad * 4] = pw;
        }
        // B-frags of P^T: B[k=key][n=q] -> lane n=c16, k=quad*8+j (+32)
        const bf16x8 pf0 = *(const bf16x8*)&Plds[wave][c16][quad * 8];
        const bf16x8 pf1 = *(const bf16x8*)&Plds[wave][c16][32 + quad * 8];

        // ---- O^T += V^T . P^T : 4 d-tiles x (K=64 over 2 mfma) ----
        #pragma unroll
        for (int dt = 0; dt < 4; ++dt) {
            const bf16x8 vf0 = *(const bf16x8*)&Vlds[dt * 16 + c16][quad * 8];
            const bf16x8 vf1 = *(const bf16x8*)&Vlds[dt * 16 + c16][32 + quad * 8];
            o[dt] = __builtin_amdgcn_mfma_f32_16x16x32_bf16(vf0, pf0, o[dt], 0, 0, 0);
            o[dt] = __builtin_amdgcn_mfma_f32_16x16x32_bf16(vf1, pf1, o[dt], 0, 0, 0);
        }
        __syncthreads();   // protect K/V tiles before next staging
    }

    // ---- epilogue: out[b][q][d], O^T reg r of tile dt is d = dt*16+quad*4+r
    const float inv = 1.0f / lrow;
    float* op = out + ((size_t)b * SQL + q0 + c16) * DH + quad * 4;
    #pragma unroll
    for (int dt = 0; dt < 4; ++dt) {
        f32x4 ov = o[dt] * inv;
        *(f32x4*)(op + dt * 16) = ov;
    }
}

extern "C" void kernel_launch(void* const* d_in, const int* in_sizes, int n_in,
                              void* d_out, int out_size, void* d_ws, size_t ws_size,
                              hipStream_t stream) {
    const float* Q  = (const float*)d_in[0];
    const float* K  = (const float*)d_in[1];
    const float* V  = (const float*)d_in[2];
    const int*   vl = (const int*)d_in[3];
    float* out = (float*)d_out;

    unsigned short* Qb = (unsigned short*)d_ws;                    // 4 MB
    unsigned short* Kb = Qb + (size_t)NB * SQL * DH;               // 4 MB
    unsigned short* Vt = Kb + (size_t)NB * SKL * DH;               // 4 MB

    prep_kernel<<<dim3(2560), dim3(256), 0, stream>>>(Q, K, V, Qb, Kb, Vt);
    attn_kernel<<<dim3(SQL / 64, NB), dim3(256), 0, stream>>>(Qb, Kb, Vt, vl, out);
}

// Round 2
// 110.993 us; speedup vs baseline: 1.0749x; 1.0749x over previous
//
#include <hip/hip_runtime.h>

#define NB 16
#define SQL 2048
#define SKL 2048
#define DH 64
#define NSPLIT 4
#define CHUNK 512          // keys per split = 8 tiles of 64

typedef __attribute__((ext_vector_type(8))) short bf16x8;
typedef __attribute__((ext_vector_type(4))) unsigned short u16x4;
typedef __attribute__((ext_vector_type(8))) unsigned short u16x8;
typedef __attribute__((ext_vector_type(4))) float f32x4;

#define LOG2E 1.4426950408889634f
#define K1 (0.125f * LOG2E)   // 1/sqrt(64) folded into exp2 argument

__device__ __forceinline__ unsigned short f2bf(float f) {
    unsigned int u = __builtin_bit_cast(unsigned int, f);
    u += 0x7fffu + ((u >> 16) & 1u);
    return (unsigned short)(u >> 16);
}

// ---------------------------------------------------------------------------
// Prep: Q,K fp32->bf16 (blocks 0..2047), V fp32 -> V^T bf16 (blocks 2048..2559)
// ---------------------------------------------------------------------------
__global__ __launch_bounds__(256) void prep_kernel(
    const float* __restrict__ Q, const float* __restrict__ K,
    const float* __restrict__ V,
    unsigned short* __restrict__ Qb, unsigned short* __restrict__ Kb,
    unsigned short* __restrict__ Vt) {
    const int blk = blockIdx.x;
    if (blk < 2048) {
        const float* src = (blk < 1024) ? Q : K;
        unsigned short* dst = (blk < 1024) ? Qb : Kb;
        const size_t base = ((size_t)(blk & 1023) * 256 + threadIdx.x) * 8;
        float4 a = *(const float4*)(src + base);
        float4 b = *(const float4*)(src + base + 4);
        u16x8 o;
        o[0] = f2bf(a.x); o[1] = f2bf(a.y); o[2] = f2bf(a.z); o[3] = f2bf(a.w);
        o[4] = f2bf(b.x); o[5] = f2bf(b.y); o[6] = f2bf(b.z); o[7] = f2bf(b.w);
        *(u16x8*)(dst + base) = o;
    } else {
        const int t  = blk - 2048;
        const int b  = t >> 5;
        const int kb = (t & 31) << 6;
        __shared__ float tile[64][65];
        const int tid = threadIdx.x;
        {
            const int r  = tid >> 2;
            const int cg = (tid & 3) << 4;
            const float* vsrc = V + ((size_t)b * SKL + (kb + r)) * DH;
            #pragma unroll
            for (int i = 0; i < 4; ++i) {
                float4 x = *(const float4*)(vsrc + cg + i * 4);
                tile[r][cg + i*4 + 0] = x.x;
                tile[r][cg + i*4 + 1] = x.y;
                tile[r][cg + i*4 + 2] = x.z;
                tile[r][cg + i*4 + 3] = x.w;
            }
        }
        __syncthreads();
        {
            const int d  = tid >> 2;
            const int kg = (tid & 3) << 4;
            unsigned short* dst = Vt + ((size_t)b * DH + d) * SKL + kb + kg;
            u16x8 o0, o1;
            #pragma unroll
            for (int j = 0; j < 8; ++j) o0[j] = f2bf(tile[kg + j][d]);
            #pragma unroll
            for (int j = 0; j < 8; ++j) o1[j] = f2bf(tile[kg + 8 + j][d]);
            *(u16x8*)(dst)     = o0;
            *(u16x8*)(dst + 8) = o1;
        }
    }
}

// ---------------------------------------------------------------------------
// Flash attention with key-split. Block = 4 waves, 64 q-rows (16/wave),
// split covers CHUNK keys. XOR-swizzled LDS (chunk ^ row&7, pitch 64) ->
// all b128 LDS ops conflict-free. Register preload pipelines tile t+1's
// global loads behind tile t's compute. Partials (unnormalized O, m, l) to ws.
// ---------------------------------------------------------------------------
__global__ __launch_bounds__(256, 4) void attn_kernel(
    const unsigned short* __restrict__ Qb,
    const unsigned short* __restrict__ Kb,
    const unsigned short* __restrict__ Vt,
    const int* __restrict__ valid_lens,
    float* __restrict__ Opart,
    float2* __restrict__ MLpart) {
    const int qblk  = blockIdx.x;
    const int split = blockIdx.y;
    const int b     = blockIdx.z;

    const int valid  = valid_lens[b];
    const int kstart = split * CHUNK;
    if (kstart >= valid) return;                 // empty split: no partial
    const int kend   = (valid < kstart + CHUNK) ? valid : (kstart + CHUNK);
    const int ntiles = (kend - kstart + 63) >> 6;

    const int tid  = threadIdx.x;
    const int wave = tid >> 6;
    const int lane = tid & 63;
    const int c16  = lane & 15;
    const int quad = lane >> 4;
    const int h    = c16 & 7;                    // swizzle key

    __shared__ unsigned short Klds[64][64];      // [key][d], chunk^=(key&7)
    __shared__ unsigned short Vlds[64][64];      // [d][key], chunk^=(d&7)
    __shared__ unsigned short Plds[4][16][64];   // per-wave [q][key], swizzled

    // Q B-fragments (loop-invariant): lane n=c16 (q), k=quad*8+j
    const int q0 = qblk * 64 + wave * 16;
    const unsigned short* qptr = Qb + ((size_t)b * SQL + q0 + c16) * DH;
    const bf16x8 qf0 = *(const bf16x8*)(qptr + quad * 8);
    const bf16x8 qf1 = *(const bf16x8*)(qptr + 32 + quad * 8);

    const unsigned short* kbase = Kb + (size_t)b * SKL * DH;
    const unsigned short* vbase = Vt + (size_t)b * DH * SKL;

    const f32x4 zero = {0.f, 0.f, 0.f, 0.f};
    f32x4 o[4];
    #pragma unroll
    for (int i = 0; i < 4; ++i) o[i] = zero;
    float mrow = -1e30f, lrow = 0.f;

    // staging registers (tile pipeline)
    u16x8 kreg[2], vreg[2];
    {
        #pragma unroll
        for (int i = 0; i < 2; ++i) {
            const int c = i * 256 + tid, r = c >> 3, col = (c & 7) << 3;
            kreg[i] = *(const u16x8*)(kbase + (size_t)(kstart + r) * DH + col);
            vreg[i] = *(const u16x8*)(vbase + (size_t)r * SKL + kstart + col);
        }
    }

    for (int kt = 0; kt < ntiles; ++kt) {
        const int kb = kstart + (kt << 6);
        __syncthreads();                         // prev tile's LDS reads done
        #pragma unroll
        for (int i = 0; i < 2; ++i) {
            const int c = i * 256 + tid, r = c >> 3;
            const int pc = ((c & 7) ^ (r & 7)) << 3;
            *(u16x8*)&Klds[r][pc] = kreg[i];
            *(u16x8*)&Vlds[r][pc] = vreg[i];
        }
        __syncthreads();
        if (kt + 1 < ntiles) {                   // preload next tile -> regs
            const int kn = kb + 64;
            #pragma unroll
            for (int i = 0; i < 2; ++i) {
                const int c = i * 256 + tid, r = c >> 3, col = (c & 7) << 3;
                kreg[i] = *(const u16x8*)(kbase + (size_t)(kn + r) * DH + col);
                vreg[i] = *(const u16x8*)(vbase + (size_t)r * SKL + kn + col);
            }
        }

        // ---- S^T = K . Q^T : 4 key-tiles x (K=64 over 2 mfma) ----
        f32x4 s[4];
        #pragma unroll
        for (int t = 0; t < 4; ++t) {
            s[t] = zero;
            const bf16x8 kf0 = *(const bf16x8*)&Klds[t*16 + c16][(quad       ^ h) << 3];
            const bf16x8 kf1 = *(const bf16x8*)&Klds[t*16 + c16][((quad + 4) ^ h) << 3];
            s[t] = __builtin_amdgcn_mfma_f32_16x16x32_bf16(kf0, qf0, s[t], 0, 0, 0);
            s[t] = __builtin_amdgcn_mfma_f32_16x16x32_bf16(kf1, qf1, s[t], 0, 0, 0);
        }

        // ---- mask boundary tile (wave-uniform branch) ----
        if (kb + 64 > kend) {
            #pragma unroll
            for (int t = 0; t < 4; ++t)
                #pragma unroll
                for (int r = 0; r < 4; ++r)
                    if (kb + t * 16 + quad * 4 + r >= kend) s[t][r] = -1e30f;
        }

        // ---- online softmax; q-column is per-lane scalar state ----
        float tmax = -1e30f;
        #pragma unroll
        for (int t = 0; t < 4; ++t)
            #pragma unroll
            for (int r = 0; r < 4; ++r) tmax = fmaxf(tmax, s[t][r]);
        tmax = fmaxf(tmax, __shfl_xor(tmax, 16));
        tmax = fmaxf(tmax, __shfl_xor(tmax, 32));

        const float mnew  = fmaxf(mrow, 0.125f * tmax);
        const float alpha = exp2f((mrow - mnew) * LOG2E);
        const float mk    = mnew * LOG2E;
        float rs = 0.f;
        #pragma unroll
        for (int t = 0; t < 4; ++t)
            #pragma unroll
            for (int r = 0; r < 4; ++r) {
                const float p = exp2f(fmaf(s[t][r], K1, -mk));
                s[t][r] = p;
                rs += p;
            }
        rs += __shfl_xor(rs, 16);
        rs += __shfl_xor(rs, 32);
        lrow = lrow * alpha + rs;
        mrow = mnew;
        #pragma unroll
        for (int i = 0; i < 4; ++i) o[i] *= alpha;

        // ---- P -> LDS (bf16, swizzled), then read back as B-frags ----
        #pragma unroll
        for (int t = 0; t < 4; ++t) {
            u16x4 pw;
            pw[0] = f2bf(s[t][0]); pw[1] = f2bf(s[t][1]);
            pw[2] = f2bf(s[t][2]); pw[3] = f2bf(s[t][3]);
            const int ch = 2 * t + (quad >> 1);
            *(u16x4*)&Plds[wave][c16][((ch ^ h) << 3) + ((quad & 1) << 2)] = pw;
        }
        const bf16x8 pf0 = *(const bf16x8*)&Plds[wave][c16][(quad       ^ h) << 3];
        const bf16x8 pf1 = *(const bf16x8*)&Plds[wave][c16][((quad + 4) ^ h) << 3];

        // ---- O^T += V^T . P^T : 4 d-tiles x (K=64 over 2 mfma) ----
        #pragma unroll
        for (int dt = 0; dt < 4; ++dt) {
            const bf16x8 vf0 = *(const bf16x8*)&Vlds[dt*16 + c16][(quad       ^ h) << 3];
            const bf16x8 vf1 = *(const bf16x8*)&Vlds[dt*16 + c16][((quad + 4) ^ h) << 3];
            o[dt] = __builtin_amdgcn_mfma_f32_16x16x32_bf16(vf0, pf0, o[dt], 0, 0, 0);
            o[dt] = __builtin_amdgcn_mfma_f32_16x16x32_bf16(vf1, pf1, o[dt], 0, 0, 0);
        }
    }

    // ---- write unnormalized partials: Opart[b][split][q][d], ML[b][split][q]
    float* op = Opart + (((size_t)b * NSPLIT + split) * SQL + q0 + c16) * DH + quad * 4;
    #pragma unroll
    for (int dt = 0; dt < 4; ++dt) *(f32x4*)(op + dt * 16) = o[dt];
    if (quad == 0)
        MLpart[((size_t)b * NSPLIT + split) * SQL + q0 + c16] = make_float2(mrow, lrow);
}

// ---------------------------------------------------------------------------
// Combine partials: out = (sum_s exp(m_s - M) O_s) / (sum_s l_s exp(m_s - M))
// ---------------------------------------------------------------------------
__global__ __launch_bounds__(256) void reduce_kernel(
    const float* __restrict__ Opart, const float2* __restrict__ MLpart,
    const int* __restrict__ valid_lens, float* __restrict__ out) {
    const int b   = blockIdx.y;
    const int tid = threadIdx.x;
    const int q   = blockIdx.x * 64 + (tid >> 2);
    const int dg  = (tid & 3) << 4;
    const int ns  = (valid_lens[b] + CHUNK - 1) / CHUNK;   // >= 1

    float m[NSPLIT], l[NSPLIT];
    float M = -1e30f;
    for (int s = 0; s < ns; ++s) {
        float2 ml = MLpart[((size_t)b * NSPLIT + s) * SQL + q];
        m[s] = ml.x; l[s] = ml.y;
        M = fmaxf(M, ml.x);
    }
    float L = 0.f;
    f32x4 acc[4];
    #pragma unroll
    for (int i = 0; i < 4; ++i) acc[i] = (f32x4){0.f, 0.f, 0.f, 0.f};
    for (int s = 0; s < ns; ++s) {
        const float w = exp2f((m[s] - M) * LOG2E);
        L += l[s] * w;
        const float* p = Opart + (((size_t)b * NSPLIT + s) * SQL + q) * DH + dg;
        #pragma unroll
        for (int i = 0; i < 4; ++i) acc[i] += w * *(const f32x4*)(p + i * 4);
    }
    const float inv = 1.0f / L;
    float* op = out + ((size_t)b * SQL + q) * DH + dg;
    #pragma unroll
    for (int i = 0; i < 4; ++i) *(f32x4*)(op + i * 4) = acc[i] * inv;
}

extern "C" void kernel_launch(void* const* d_in, const int* in_sizes, int n_in,
                              void* d_out, int out_size, void* d_ws, size_t ws_size,
                              hipStream_t stream) {
    const float* Q  = (const float*)d_in[0];
    const float* K  = (const float*)d_in[1];
    const float* V  = (const float*)d_in[2];
    const int*   vl = (const int*)d_in[3];
    float* out = (float*)d_out;

    unsigned short* Qb = (unsigned short*)d_ws;                      // 4 MB
    unsigned short* Kb = Qb + (size_t)NB * SQL * DH;                 // 4 MB
    unsigned short* Vt = Kb + (size_t)NB * SKL * DH;                 // 4 MB
    float*  Opart  = (float*)(Vt + (size_t)NB * SKL * DH);           // 33.5 MB
    float2* MLpart = (float2*)(Opart + (size_t)NB * NSPLIT * SQL * DH); // 1 MB

    prep_kernel<<<dim3(2560), dim3(256), 0, stream>>>(Q, K, V, Qb, Kb, Vt);
    attn_kernel<<<dim3(SQL / 64, NSPLIT, NB), dim3(256), 0, stream>>>(
        Qb, Kb, Vt, vl, Opart, MLpart);
    reduce_kernel<<<dim3(SQL / 64, NB), dim3(256), 0, stream>>>(
        Opart, MLpart, vl, out);
}

// Round 3
// 110.780 us; speedup vs baseline: 1.0770x; 1.0019x over previous
//
#include <hip/hip_runtime.h>

#define NB 16
#define SQL 2048
#define SKL 2048
#define DH 64
#define NSPLIT 8
#define CHUNK 256          // keys per split = 4 tiles of 64

typedef __attribute__((ext_vector_type(8)))  short bf16x8;
typedef __attribute__((ext_vector_type(4)))  unsigned short u16x4;
typedef __attribute__((ext_vector_type(8)))  unsigned short u16x8;
typedef __attribute__((ext_vector_type(4)))  float f32x4;
typedef __attribute__((ext_vector_type(16))) float f32x16;

#define LOG2E 1.4426950408889634f
#define K1 (0.125f * LOG2E)   // 1/sqrt(64) folded into exp2 argument

__device__ __forceinline__ unsigned short f2bf(float f) {
    unsigned int u = __builtin_bit_cast(unsigned int, f);
    u += 0x7fffu + ((u >> 16) & 1u);
    return (unsigned short)(u >> 16);
}
__device__ __forceinline__ float bf2f(unsigned short h) {
    return __builtin_bit_cast(float, (unsigned int)h << 16);
}

// ---------------------------------------------------------------------------
// Prep: Q,K fp32->bf16 (blocks 0..2047), V fp32 -> V^T bf16 (blocks 2048..2559)
// ---------------------------------------------------------------------------
__global__ __launch_bounds__(256) void prep_kernel(
    const float* __restrict__ Q, const float* __restrict__ K,
    const float* __restrict__ V,
    unsigned short* __restrict__ Qb, unsigned short* __restrict__ Kb,
    unsigned short* __restrict__ Vt) {
    const int blk = blockIdx.x;
    if (blk < 2048) {
        const float* src = (blk < 1024) ? Q : K;
        unsigned short* dst = (blk < 1024) ? Qb : Kb;
        const size_t base = ((size_t)(blk & 1023) * 256 + threadIdx.x) * 8;
        float4 a = *(const float4*)(src + base);
        float4 b = *(const float4*)(src + base + 4);
        u16x8 o;
        o[0] = f2bf(a.x); o[1] = f2bf(a.y); o[2] = f2bf(a.z); o[3] = f2bf(a.w);
        o[4] = f2bf(b.x); o[5] = f2bf(b.y); o[6] = f2bf(b.z); o[7] = f2bf(b.w);
        *(u16x8*)(dst + base) = o;
    } else {
        const int t  = blk - 2048;
        const int b  = t >> 5;
        const int kb = (t & 31) << 6;
        __shared__ float tile[64][65];
        const int tid = threadIdx.x;
        {
            const int r  = tid >> 2;
            const int cg = (tid & 3) << 4;
            const float* vsrc = V + ((size_t)b * SKL + (kb + r)) * DH;
            #pragma unroll
            for (int i = 0; i < 4; ++i) {
                float4 x = *(const float4*)(vsrc + cg + i * 4);
                tile[r][cg + i*4 + 0] = x.x;
                tile[r][cg + i*4 + 1] = x.y;
                tile[r][cg + i*4 + 2] = x.z;
                tile[r][cg + i*4 + 3] = x.w;
            }
        }
        __syncthreads();
        {
            const int d  = tid >> 2;
            const int kg = (tid & 3) << 4;
            unsigned short* dst = Vt + ((size_t)b * DH + d) * SKL + kb + kg;
            u16x8 o0, o1;
            #pragma unroll
            for (int j = 0; j < 8; ++j) o0[j] = f2bf(tile[kg + j][d]);
            #pragma unroll
            for (int j = 0; j < 8; ++j) o1[j] = f2bf(tile[kg + 8 + j][d]);
            *(u16x8*)(dst)     = o0;
            *(u16x8*)(dst + 8) = o1;
        }
    }
}

// ---------------------------------------------------------------------------
// Flash attention, S^T/O^T form, 32x32x16 MFMA. Block = 4 waves, 128 q-rows
// (32/wave, q-col = lane&31). K-tile 64 keys. 16B-unit XOR-swizzled LDS.
// Lane l and l^32 split the 64 key-rows of one q -> softmax needs 1 shuffle.
// Partials (bf16 O, m, l) per split to ws; reduce combines.
// ---------------------------------------------------------------------------
__global__ __launch_bounds__(256, 3) void attn_kernel(
    const unsigned short* __restrict__ Qb,
    const unsigned short* __restrict__ Kb,
    const unsigned short* __restrict__ Vt,
    const int* __restrict__ valid_lens,
    unsigned short* __restrict__ Opart,
    float2* __restrict__ MLpart) {
    const int qblk  = blockIdx.x;
    const int split = blockIdx.y;
    const int b     = blockIdx.z;

    const int valid  = valid_lens[b];
    const int kstart = split * CHUNK;
    if (kstart >= valid) return;                 // empty split: no partial
    const int kend   = (valid < kstart + CHUNK) ? valid : (kstart + CHUNK);
    const int ntiles = (kend - kstart + 63) >> 6;

    const int tid  = threadIdx.x;
    const int wave = tid >> 6;
    const int lane = tid & 63;
    const int l31  = lane & 31;
    const int h2   = lane >> 5;
    const int sw   = l31 & 7;                    // swizzle key

    __shared__ unsigned short Klds[64][64];      // [key][d], unit^=(key&7)
    __shared__ unsigned short Vlds[64][64];      // [d][key], unit^=(d&7)
    __shared__ unsigned short Plds[4][32][64];   // per-wave [q][key], unit^=(q&7)

    // Q B-fragments: B[k=d][n=q], lane n=l31, k = ks*16 + h2*8 + j
    const int q0 = qblk * 128 + wave * 32;
    const unsigned short* qptr = Qb + ((size_t)b * SQL + q0 + l31) * DH + h2 * 8;
    bf16x8 qf[4];
    #pragma unroll
    for (int ks = 0; ks < 4; ++ks) qf[ks] = *(const bf16x8*)(qptr + ks * 16);

    const unsigned short* kbase = Kb + (size_t)b * SKL * DH;
    const unsigned short* vbase = Vt + (size_t)b * DH * SKL;

    f32x16 o[2];
    #pragma unroll
    for (int i = 0; i < 2; ++i)
        #pragma unroll
        for (int r = 0; r < 16; ++r) o[i][r] = 0.f;
    float mrow = -1e30f, lrow = 0.f;

    // staging registers (tile pipeline)
    u16x8 kreg[2], vreg[2];
    #pragma unroll
    for (int i = 0; i < 2; ++i) {
        const int c = i * 256 + tid, r = c >> 3, col = (c & 7) << 3;
        kreg[i] = *(const u16x8*)(kbase + (size_t)(kstart + r) * DH + col);
        vreg[i] = *(const u16x8*)(vbase + (size_t)r * SKL + kstart + col);
    }

    for (int kt = 0; kt < ntiles; ++kt) {
        const int kb = kstart + (kt << 6);
        __syncthreads();                         // prev tile's LDS reads done
        #pragma unroll
        for (int i = 0; i < 2; ++i) {
            const int c = i * 256 + tid, r = c >> 3;
            const int pc = ((c & 7) ^ (r & 7)) << 3;
            *(u16x8*)&Klds[r][pc] = kreg[i];
            *(u16x8*)&Vlds[r][pc] = vreg[i];
        }
        __syncthreads();
        if (kt + 1 < ntiles) {                   // preload next tile -> regs
            const int kn = kb + 64;
            #pragma unroll
            for (int i = 0; i < 2; ++i) {
                const int c = i * 256 + tid, r = c >> 3, col = (c & 7) << 3;
                kreg[i] = *(const u16x8*)(kbase + (size_t)(kn + r) * DH + col);
                vreg[i] = *(const u16x8*)(vbase + (size_t)r * SKL + kn + col);
            }
        }

        // ---- S^T = K . Q^T : 2 key-subtiles x 4 K-steps of 32x32x16 ----
        f32x16 s[2];
        #pragma unroll
        for (int t = 0; t < 2; ++t) {
            #pragma unroll
            for (int r = 0; r < 16; ++r) s[t][r] = 0.f;
            #pragma unroll
            for (int ks = 0; ks < 4; ++ks) {
                const bf16x8 kf = *(const bf16x8*)
                    &Klds[t * 32 + l31][((2 * ks + h2) ^ sw) << 3];
                s[t] = __builtin_amdgcn_mfma_f32_32x32x16_bf16(kf, qf[ks], s[t], 0, 0, 0);
            }
        }

        // ---- mask boundary tile (wave-uniform branch) ----
        // key(reg) = kb + t*32 + (reg&3) + 8*(reg>>2) + 4*h2
        if (kb + 64 > kend) {
            #pragma unroll
            for (int t = 0; t < 2; ++t)
                #pragma unroll
                for (int r = 0; r < 16; ++r)
                    if (kb + t * 32 + (r & 3) + 8 * (r >> 2) + 4 * h2 >= kend)
                        s[t][r] = -1e30f;
        }

        // ---- online softmax; q is per-lane, rows split across lane^32 ----
        float tmax = -1e30f;
        #pragma unroll
        for (int t = 0; t < 2; ++t)
            #pragma unroll
            for (int r = 0; r < 16; ++r) tmax = fmaxf(tmax, s[t][r]);
        tmax = fmaxf(tmax, __shfl_xor(tmax, 32));

        const float mnew  = fmaxf(mrow, 0.125f * tmax);
        const float alpha = exp2f((mrow - mnew) * LOG2E);
        const float mk    = mnew * LOG2E;
        float rs = 0.f;
        #pragma unroll
        for (int t = 0; t < 2; ++t)
            #pragma unroll
            for (int r = 0; r < 16; ++r) {
                const float p = exp2f(fmaf(s[t][r], K1, -mk));
                s[t][r] = p;
                rs += p;
            }
        rs += __shfl_xor(rs, 32);
        lrow = lrow * alpha + rs;
        mrow = mnew;
        #pragma unroll
        for (int i = 0; i < 2; ++i)
            #pragma unroll
            for (int r = 0; r < 16; ++r) o[i][r] *= alpha;

        // ---- P -> LDS (bf16, swizzled): 8 writes of 4 contiguous keys ----
        #pragma unroll
        for (int t = 0; t < 2; ++t)
            #pragma unroll
            for (int g = 0; g < 4; ++g) {
                u16x4 pw;
                pw[0] = f2bf(s[t][g * 4 + 0]); pw[1] = f2bf(s[t][g * 4 + 1]);
                pw[2] = f2bf(s[t][g * 4 + 2]); pw[3] = f2bf(s[t][g * 4 + 3]);
                const int unit = (4 * t + g) ^ sw;
                *(u16x4*)&Plds[wave][l31][(unit << 3) + (h2 << 2)] = pw;
            }
        // B-frags of P^T: lane n=l31(q), k = ks*16 + h2*8 + j (wave-local, no barrier)
        bf16x8 pf[4];
        #pragma unroll
        for (int ks = 0; ks < 4; ++ks)
            pf[ks] = *(const bf16x8*)&Plds[wave][l31][((2 * ks + h2) ^ sw) << 3];

        // ---- O^T += V^T . P^T : 2 d-subtiles x 4 K-steps ----
        #pragma unroll
        for (int dt = 0; dt < 2; ++dt)
            #pragma unroll
            for (int ks = 0; ks < 4; ++ks) {
                const bf16x8 vf = *(const bf16x8*)
                    &Vlds[dt * 32 + l31][((2 * ks + h2) ^ sw) << 3];
                o[dt] = __builtin_amdgcn_mfma_f32_32x32x16_bf16(vf, pf[ks], o[dt], 0, 0, 0);
            }
    }

    // ---- partials: Opart[b][split][q][d] bf16; d = dt*32 + 8g + 4h2 + r ----
    unsigned short* op = Opart +
        (((size_t)b * NSPLIT + split) * SQL + q0 + l31) * DH;
    #pragma unroll
    for (int dt = 0; dt < 2; ++dt)
        #pragma unroll
        for (int g = 0; g < 4; ++g) {
            u16x4 ow;
            ow[0] = f2bf(o[dt][g * 4 + 0]); ow[1] = f2bf(o[dt][g * 4 + 1]);
            ow[2] = f2bf(o[dt][g * 4 + 2]); ow[3] = f2bf(o[dt][g * 4 + 3]);
            *(u16x4*)(op + dt * 32 + 8 * g + 4 * h2) = ow;
        }
    if (h2 == 0)
        MLpart[((size_t)b * NSPLIT + split) * SQL + q0 + l31] =
            make_float2(mrow, lrow);
}

// ---------------------------------------------------------------------------
// Combine partials: out = (sum_s exp(m_s - M) O_s) / (sum_s l_s exp(m_s - M))
// ---------------------------------------------------------------------------
__global__ __launch_bounds__(256) void reduce_kernel(
    const unsigned short* __restrict__ Opart, const float2* __restrict__ MLpart,
    const int* __restrict__ valid_lens, float* __restrict__ out) {
    const int b   = blockIdx.y;
    const int tid = threadIdx.x;
    const int q   = blockIdx.x * 64 + (tid >> 2);
    const int dg  = (tid & 3) << 4;
    const int ns  = (valid_lens[b] + CHUNK - 1) / CHUNK;   // 1..8

    float m[NSPLIT], l[NSPLIT];
    float M = -1e30f;
    for (int s = 0; s < ns; ++s) {
        float2 ml = MLpart[((size_t)b * NSPLIT + s) * SQL + q];
        m[s] = ml.x; l[s] = ml.y;
        M = fmaxf(M, ml.x);
    }
    float L = 0.f;
    float acc[16];
    #pragma unroll
    for (int i = 0; i < 16; ++i) acc[i] = 0.f;
    for (int s = 0; s < ns; ++s) {
        const float w = exp2f((m[s] - M) * LOG2E);
        L += l[s] * w;
        const unsigned short* p =
            Opart + (((size_t)b * NSPLIT + s) * SQL + q) * DH + dg;
        u16x8 a0 = *(const u16x8*)(p);
        u16x8 a1 = *(const u16x8*)(p + 8);
        #pragma unroll
        for (int i = 0; i < 8; ++i) acc[i]     += w * bf2f(a0[i]);
        #pragma unroll
        for (int i = 0; i < 8; ++i) acc[8 + i] += w * bf2f(a1[i]);
    }
    const float inv = 1.0f / L;
    float* op = out + ((size_t)b * SQL + q) * DH + dg;
    f32x4 ov;
    #pragma unroll
    for (int i = 0; i < 4; ++i) {
        ov[0] = acc[i*4+0] * inv; ov[1] = acc[i*4+1] * inv;
        ov[2] = acc[i*4+2] * inv; ov[3] = acc[i*4+3] * inv;
        *(f32x4*)(op + i * 4) = ov;
    }
}

extern "C" void kernel_launch(void* const* d_in, const int* in_sizes, int n_in,
                              void* d_out, int out_size, void* d_ws, size_t ws_size,
                              hipStream_t stream) {
    const float* Q  = (const float*)d_in[0];
    const float* K  = (const float*)d_in[1];
    const float* V  = (const float*)d_in[2];
    const int*   vl = (const int*)d_in[3];
    float* out = (float*)d_out;

    unsigned short* Qb = (unsigned short*)d_ws;                      // 4 MB
    unsigned short* Kb = Qb + (size_t)NB * SQL * DH;                 // 4 MB
    unsigned short* Vt = Kb + (size_t)NB * SKL * DH;                 // 4 MB
    unsigned short* Opart = Vt + (size_t)NB * SKL * DH;              // 33.5 MB bf16
    float2* MLpart = (float2*)(Opart + (size_t)NB * NSPLIT * SQL * DH); // 2 MB

    prep_kernel<<<dim3(2560), dim3(256), 0, stream>>>(Q, K, V, Qb, Kb, Vt);
    attn_kernel<<<dim3(SQL / 128, NSPLIT, NB), dim3(256), 0, stream>>>(
        Qb, Kb, Vt, vl, Opart, MLpart);
    reduce_kernel<<<dim3(SQL / 64, NB), dim3(256), 0, stream>>>(
        Opart, MLpart, vl, out);
}